// Round 1
// baseline (131.884 us; speedup 1.0000x reference)
//
#include <hip/hip_runtime.h>

// pos/seq_lens fill for ragged batch metadata.
// d_out layout (int32): [0, num_tokens) = pos, [num_tokens, num_tokens+max_num_reqs) = seq_lens.
//
// Memory-bound: 64 MiB pos write stream dominates. Strategy:
//  - 256 threads/block, 16 tokens/thread (4x int4 coalesced stores -> full cachelines).
//  - One binary search (upper_bound over qsl, 8193 ints, L1-resident) per thread,
//    then linear advance across request boundaries within the thread's 16 tokens.
//  - base = nct[idx_mapping[r]] - qsl[r] so pos[t] = base + t.
//  - Tail blocks of the same grid write seq_lens (incl. zeros past num_reqs,
//    since the harness poisons d_out with 0xAA).

#define TPB 256
#define TOK_PER_THREAD 16   // 4 x int4
#define TOK_PER_BLOCK (TPB * TOK_PER_THREAD)   // 4096
#define SEQ_PER_BLOCK (TPB * 4)                // 1024

__global__ __launch_bounds__(TPB) void pos_seq_kernel(
    const int* __restrict__ idx_mapping,
    const int* __restrict__ qsl,          // [num_reqs+1]
    const int* __restrict__ nct,          // [max_num_reqs]
    int* __restrict__ pos_out,            // [num_tokens]
    int* __restrict__ seq_out,            // [max_num_reqs]
    int num_reqs, int max_num_reqs, int num_tokens,
    int pos_blocks)
{
    int b = blockIdx.x;

    if (b >= pos_blocks) {
        // ---- seq_lens part ----
        int i = (b - pos_blocks) * SEQ_PER_BLOCK + (int)threadIdx.x * 4;
        if (i >= max_num_reqs) return;
        if (i + 4 <= max_num_reqs) {
            int4 v;
            int* vp = (int*)&v;
            #pragma unroll
            for (int k = 0; k < 4; ++k) {
                int idx = i + k;
                int val = 0;
                if (idx < num_reqs)
                    val = nct[idx_mapping[idx]] + (qsl[idx + 1] - qsl[idx]);
                vp[k] = val;
            }
            *(int4*)(seq_out + i) = v;
        } else {
            for (int idx = i; idx < max_num_reqs; ++idx) {
                int val = 0;
                if (idx < num_reqs)
                    val = nct[idx_mapping[idx]] + (qsl[idx + 1] - qsl[idx]);
                seq_out[idx] = val;
            }
        }
        return;
    }

    // ---- pos part ----
    long long t0l = (long long)b * TOK_PER_BLOCK + (long long)threadIdx.x * TOK_PER_THREAD;
    if (t0l >= num_tokens) return;
    int t0 = (int)t0l;
    int t = t0;

    // upper_bound: last index r in [0, num_reqs] with qsl[r] <= t.
    // qsl[0]=0 <= t always; qsl[num_reqs]=num_tokens > t, so r <= num_reqs-1.
    int l = 0, h = num_reqs + 1;
    while (h - l > 1) {
        int mid = (l + h) >> 1;
        if (qsl[mid] <= t) l = mid; else h = mid;
    }
    int r = l;
    int next = qsl[r + 1];
    int base = nct[idx_mapping[r]] - qsl[r];

    if (t0 + TOK_PER_THREAD <= num_tokens) {
        #pragma unroll
        for (int g = 0; g < TOK_PER_THREAD / 4; ++g) {
            int4 v;
            int* vp = (int*)&v;
            #pragma unroll
            for (int k = 0; k < 4; ++k) {
                while (t >= next) {              // skips empty requests too
                    ++r;
                    next = qsl[r + 1];
                    base = nct[idx_mapping[r]] - qsl[r];
                }
                vp[k] = base + t;
                ++t;
            }
            *(int4*)(pos_out + t0 + g * 4) = v;
        }
    } else {
        // generic tail (not hit for the benchmark sizes, kept for safety)
        for (; t < num_tokens && t < t0 + TOK_PER_THREAD; ++t) {
            while (t >= next) {
                ++r;
                next = qsl[r + 1];
                base = nct[idx_mapping[r]] - qsl[r];
            }
            pos_out[t] = base + t;
        }
    }
}

extern "C" void kernel_launch(void* const* d_in, const int* in_sizes, int n_in,
                              void* d_out, int out_size, void* d_ws, size_t ws_size,
                              hipStream_t stream) {
    const int* idx_mapping = (const int*)d_in[0];
    const int* qsl         = (const int*)d_in[1];
    const int* nct         = (const int*)d_in[2];
    // d_in[3] (pos buffer) and d_in[4] (seq_lens buffer) are unused inputs.

    int num_reqs     = in_sizes[0];
    int max_num_reqs = in_sizes[2];
    int num_tokens   = in_sizes[3];

    int* out = (int*)d_out;
    int* pos_out = out;
    int* seq_out = out + num_tokens;

    int pos_blocks = (num_tokens + TOK_PER_BLOCK - 1) / TOK_PER_BLOCK;     // 4096
    int seq_blocks = (max_num_reqs + SEQ_PER_BLOCK - 1) / SEQ_PER_BLOCK;   // 16

    dim3 grid(pos_blocks + seq_blocks), block(TPB);
    pos_seq_kernel<<<grid, block, 0, stream>>>(
        idx_mapping, qsl, nct, pos_out, seq_out,
        num_reqs, max_num_reqs, num_tokens, pos_blocks);
}